// Round 18
// baseline (238.728 us; speedup 1.0000x reference)
//
#include <hip/hip_runtime.h>
#include <hip/hip_bf16.h>

#define B_SZ 1024
#define C_SZ 100
#define D_SZ 768

// ---- 8-phase main kernel geometry ----
#define BM 256                 // d-rows per block
#define BN 256                 // b-cols per block
#define BK 64                  // e per K-tile
#define NKT (D_SZ / BK)        // 12
#define NTHREADS 512           // 8 waves: 2(M) x 4(N), wave tile 128x64
#define TPC 12                 // tiles/class: 3 M x 4 N
#define A_TILE (BM * BK)       // 16384 ushorts = 32 KB per buffer
#define X_TILE (BN * BK)

#define TBL_ELEMS ((size_t)C_SZ * D_SZ)          // 76,800
#define AP_ELEMS  ((size_t)C_SZ * D_SZ * D_SZ)   // 58,982,400
#define RB_ELEMS  ((size_t)B_SZ * D_SZ)          // 786,432

typedef float f32x4 __attribute__((ext_vector_type(4)));
typedef short short8 __attribute__((ext_vector_type(8)));

__device__ __forceinline__ ushort f2bf(float f) {
    union { __hip_bfloat16 b; ushort u; } cv; cv.b = __float2bfloat16(f); return cv.u;
}
__device__ __forceinline__ float bf2f(ushort u) {
    union { __hip_bfloat16 b; ushort us; } cv; cv.us = u; return __bfloat162float(cv.b);
}
__device__ __forceinline__ void gload_lds16(const void* g, void* l) {
    __builtin_amdgcn_global_load_lds((const __attribute__((address_space(1))) void*)g,
                                     (__attribute__((address_space(3))) void*)l, 16, 0, 0);
}

// ---- prepass A (merged): blocks 0..74 build rd/md; 75..458 cast raw->bf16 ----
__global__ __launch_bounds__(256) void prep_small(const float* __restrict__ mean,
                                                  const float* __restrict__ diag,
                                                  const float* __restrict__ raw,
                                                  float* __restrict__ rd,
                                                  float* __restrict__ md,
                                                  ushort* __restrict__ rb) {
    const int bx = (int)blockIdx.x;
    if (bx < 75) {
        const int i = (bx * 256 + (int)threadIdx.x) * 4;
        if (i < (int)TBL_ELEMS) {
            const f32x4 dv = *(const f32x4*)(diag + i);
            const f32x4 mv = *(const f32x4*)(mean + i);
            f32x4 r, m;
            r.x = 1.0f / dv.x; r.y = 1.0f / dv.y; r.z = 1.0f / dv.z; r.w = 1.0f / dv.w;
            m.x = mv.x * r.x;  m.y = mv.y * r.y;  m.z = mv.z * r.z;  m.w = mv.w * r.w;
            *(f32x4*)(rd + i) = r;
            *(f32x4*)(md + i) = m;
        }
    } else {
        const size_t i = (size_t)(bx - 75) * 256 + threadIdx.x;
        const f32x4 v0 = *(const f32x4*)(raw + i * 8);
        const f32x4 v1 = *(const f32x4*)(raw + i * 8 + 4);
        short8 p;
        p[0]=(short)f2bf(v0.x); p[1]=(short)f2bf(v0.y); p[2]=(short)f2bf(v0.z); p[3]=(short)f2bf(v0.w);
        p[4]=(short)f2bf(v1.x); p[5]=(short)f2bf(v1.y); p[6]=(short)f2bf(v1.z); p[7]=(short)f2bf(v1.w);
        *(short8*)(rb + i * 8) = p;
    }
}

// ---- prepass B: A'[c][d][e] = bf16(A*rd_c[e]); w[c][d] = dot(A_row, md_c) ----
__global__ __launch_bounds__(512) void conv_aprime(const float* __restrict__ inv,
                                                   const float* __restrict__ rd,
                                                   const float* __restrict__ md,
                                                   ushort* __restrict__ ap,
                                                   float* __restrict__ w) {
    const int lane = (int)threadIdx.x & 63;
    const int wv   = (int)threadIdx.x >> 6;
    const int ridx = (int)blockIdx.x * 8 + wv;            // c*768+d
    const int c    = ridx / D_SZ;
    const float* arow = inv + (size_t)ridx * D_SZ;
    const float* rdc  = rd + (size_t)c * D_SZ;
    const float* mdc  = md + (size_t)c * D_SZ;
    ushort* aprow = ap + (size_t)ridx * D_SZ;
    float dot = 0.f;
    #pragma unroll
    for (int j = 0; j < 3; ++j) {
        const int e = j * 256 + lane * 4;
        const f32x4 a  = *(const f32x4*)(arow + e);
        const f32x4 r4 = *(const f32x4*)(rdc + e);
        const f32x4 m4 = *(const f32x4*)(mdc + e);
        dot += a.x * m4.x + a.y * m4.y + a.z * m4.z + a.w * m4.w;
        ushort4 p;
        p.x = f2bf(a.x * r4.x); p.y = f2bf(a.y * r4.y);
        p.z = f2bf(a.z * r4.z); p.w = f2bf(a.w * r4.w);
        *(ushort4*)(aprow + e) = p;
    }
    #pragma unroll
    for (int k = 1; k < 64; k <<= 1) dot += __shfl_xor(dot, k);
    if (lane == 0) w[ridx] = dot;
}

// ---- MAIN: 8-phase-style schedule (full T3+T4+T5 port, not a graft) ----
// Per K-tile (BK=64): 4 phases {ds_read frags; issue 2 gload_lds prefetch;
// s_barrier; setprio(1); 16 MFMA; setprio(0); s_barrier}. vmcnt(0) ONCE per
// K-tile (before the last phase barrier) -> prefetch loads span 3 phases.
// Fold epilogue: out += sum_d x[b,d]*(w[d]-t[d,b])  (R9/R17-validated).
__global__ __launch_bounds__(NTHREADS, 2) void fecam_scores8(
        const float* __restrict__ raw,
        const float* __restrict__ rdT, const float* __restrict__ mdT,
        const float* __restrict__ wT,
        const ushort* __restrict__ apAll, const ushort* __restrict__ rbAll,
        float* __restrict__ out) {
    __shared__ __align__(16) ushort aLds[2 * A_TILE];   // 64 KB
    __shared__ __align__(16) ushort xLds[2 * X_TILE];   // 64 KB -> 128 KB total

    const int tid = (int)threadIdx.x;
    const int bx  = (int)blockIdx.x;

    // XCD-pinned class grouping (validated R3); 4 N-sharers per A' panel
    const int x = bx & 7;
    const int slot0 = bx >> 3;
    const int nCls  = (x < 4) ? 13 : 12;
    const int baseC = (x < 4) ? x * 13 : 52 + (x - 4) * 12;
    const int ci = slot0 / TPC;
    if (ci >= nCls) return;
    const int t  = slot0 % TPC;
    const int c  = baseC + ci;
    const int d0 = (t >> 2) * BM;      // 0..2
    const int b0 = (t & 3) * BN;       // 0..3

    const int lane = tid & 63;
    const int wid  = tid >> 6;
    const int wm   = wid >> 2;      // 0..1 (M: 128 rows)
    const int wn   = wid & 3;       // 0..3 (N: 64 cols)
    const int l15  = lane & 15;
    const int l4   = lane >> 4;

    const ushort* apc = apAll + (size_t)c * D_SZ * D_SZ + (size_t)d0 * D_SZ;
    const ushort* rbc = rbAll + (size_t)b0 * D_SZ;

    // staging: source-side XOR swizzle q = (s&7) ^ (r&7); LDS dest linear.
    // (R9-validated at BK=64: 0 bank conflicts, correctness absmax 1.0)
    auto stage_part = [&](ushort* dstbase, const ushort* src, int kt, int i) {
        const int s = tid + i * NTHREADS;   // 0..2047: row = s>>3, chunk = s&7
        const int r = s >> 3;
        const int q = (s & 7) ^ (r & 7);
        gload_lds16(src + (size_t)r * D_SZ + kt * BK + q * 8, dstbase + s * 8);
    };

    // prologue: stage K-tile 0 fully, drain, barrier
    #pragma unroll
    for (int i = 0; i < 4; ++i) {
        stage_part(aLds, apc, 0, i);
        stage_part(xLds, rbc, 0, i);
    }
    asm volatile("s_waitcnt vmcnt(0)" ::: "memory");
    __builtin_amdgcn_s_barrier();

    f32x4 acc[8][4] = {};   // wave 128(M) x 64(N)
    const int swz = l15 & 7;

    for (int kt = 0; kt < NKT; ++kt) {
        const int bf = kt & 1;
        const ushort* ab = aLds + bf * A_TILE;
        const ushort* xb = xLds + bf * X_TILE;
        ushort* anx = aLds + (bf ^ 1) * A_TILE;
        ushort* xnx = xLds + (bf ^ 1) * X_TILE;
        const bool pre = (kt + 1 < NKT);
        short8 xf[4];
        #pragma unroll
        for (int p = 0; p < 4; ++p) {
            const int kk = p >> 1;      // k-slab (K=32) of this K-tile
            const int mh = p & 1;       // m-half of the wave tile
            const int ch = (kk * 4 + l4) ^ swz;
            if (mh == 0) {              // xf reused by both m-halves of this kk
                #pragma unroll
                for (int n = 0; n < 4; ++n)
                    xf[n] = *(const short8*)(xb + ((wn * 64 + n * 16 + l15) * 8 + ch) * 8);
            }
            short8 af[4];
            #pragma unroll
            for (int m2 = 0; m2 < 4; ++m2)
                af[m2] = *(const short8*)(ab + ((wm * 128 + (mh * 4 + m2) * 16 + l15) * 8 + ch) * 8);
            if (pre) {                  // 2 prefetch loads per phase
                stage_part(anx, apc, kt + 1, p);
                stage_part(xnx, rbc, kt + 1, p);
            }
            __builtin_amdgcn_s_barrier();
            __builtin_amdgcn_s_setprio(1);
            #pragma unroll
            for (int m2 = 0; m2 < 4; ++m2)
                #pragma unroll
                for (int n = 0; n < 4; ++n)
                    acc[mh * 4 + m2][n] = __builtin_amdgcn_mfma_f32_16x16x32_bf16(
                        af[m2], xf[n], acc[mh * 4 + m2][n], 0, 0, 0);
            __builtin_amdgcn_s_setprio(0);
            if (p == 3 && pre) asm volatile("s_waitcnt vmcnt(0)" ::: "memory");
            __builtin_amdgcn_s_barrier();
        }
    }

    // ---- fold (R9/R17-validated): v[n] = sum_d x[b,d]*(w[d]-t[d,b]) ----
    // C/D layout (validated): col(b)=l15, row(d)=l4*4+j
    float v[4] = {};
    #pragma unroll
    for (int m = 0; m < 8; ++m) {
        const int dd = d0 + wm * 128 + m * 16 + l4 * 4;
        const f32x4 rd4 = *(const f32x4*)(rdT + (size_t)c * D_SZ + dd);
        const f32x4 md4 = *(const f32x4*)(mdT + (size_t)c * D_SZ + dd);
        const f32x4 w4  = *(const f32x4*)(wT + (size_t)c * D_SZ + dd);
        #pragma unroll
        for (int n = 0; n < 4; ++n) {
            const int bl = b0 + wn * 64 + n * 16 + l15;
            const f32x4 rv = *(const f32x4*)(raw + (size_t)bl * D_SZ + dd);
            v[n] += (w4.x - acc[m][n][0]) * (rv.x * rd4.x - md4.x)
                  + (w4.y - acc[m][n][1]) * (rv.y * rd4.y - md4.y)
                  + (w4.z - acc[m][n][2]) * (rv.z * rd4.z - md4.z)
                  + (w4.w - acc[m][n][3]) * (rv.w * rd4.w - md4.w);
        }
    }
    #pragma unroll
    for (int n = 0; n < 4; ++n) {
        v[n] += __shfl_xor(v[n], 16);
        v[n] += __shfl_xor(v[n], 32);
    }
    // red aliases dead aLds (all waves past final phase barrier => reads done)
    float* red = (float*)aLds;          // 8 waves x 64 floats
    if (lane < 16) {
        #pragma unroll
        for (int n = 0; n < 4; ++n) red[wid * 64 + n * 16 + l15] = v[n];
    }
    __syncthreads();
    if (tid < BN) {   // b-local = tid: wn = tid>>6, off = tid&63
        const int wno = tid >> 6;
        const int off = tid & 63;
        const float p = red[wno * 64 + off] + red[(4 + wno) * 64 + off];
        atomicAdd(out + (size_t)(b0 + tid) * C_SZ + c, p);
    }
}

// ---- fallback (no-ws): R17's MODE-0 kernel verbatim (correctness path) ----
__global__ __launch_bounds__(512, 4) void fecam_fallback(
        const float* __restrict__ raw, const float* __restrict__ mean,
        const float* __restrict__ diag, const float* __restrict__ inv,
        float* __restrict__ out) {
    __shared__ __align__(16) ushort aLds[2 * 128 * 32];
    __shared__ __align__(16) ushort xLds[2 * 256 * 32];
    __shared__ float red[8 * 64];

    const int tid = (int)threadIdx.x;
    const int bx  = (int)blockIdx.x;
    const int x = bx & 7;
    const int slot0 = bx >> 3;
    const int nCls  = (x < 4) ? 13 : 12;
    const int baseC = (x < 4) ? x * 13 : 52 + (x - 4) * 12;
    const int ci = slot0 / 24;
    if (ci >= nCls) return;
    const int t  = slot0 % 24;
    const int c  = baseC + ci;
    const int d0 = (t >> 2) * 128;
    const int b0 = (t & 3) * 256;

    const int lane = tid & 63;
    const int wid  = tid >> 6;
    const int wm   = wid >> 2;
    const int wn   = wid & 3;
    const int l15  = lane & 15;
    const int l4   = lane >> 4;
    const float* Af = inv + (size_t)c * D_SZ * D_SZ;

    auto stage_a = [&](ushort* dst, int kt) {
        const int s = tid;
        const int r = s >> 2;
        const int q = (s & 3) ^ ((r >> 1) & 3);
        const float* gp = Af + (size_t)(d0 + r) * D_SZ + kt * 32 + q * 8;
        const f32x4 a0 = *(const f32x4*)gp;
        const f32x4 a1 = *(const f32x4*)(gp + 4);
        short8 p;
        p[0]=(short)f2bf(a0.x); p[1]=(short)f2bf(a0.y); p[2]=(short)f2bf(a0.z); p[3]=(short)f2bf(a0.w);
        p[4]=(short)f2bf(a1.x); p[5]=(short)f2bf(a1.y); p[6]=(short)f2bf(a1.z); p[7]=(short)f2bf(a1.w);
        *(short8*)(dst + s * 8) = p;
    };
    auto stage_x = [&](ushort* dst, int kt) {
        #pragma unroll
        for (int i = 0; i < 2; ++i) {
            const int s = tid + i * 512;
            const int r = s >> 2;
            const int q = (s & 3) ^ ((r >> 1) & 3);
            const int e = kt * 32 + q * 8;
            const float* rp = raw + (size_t)(b0 + r) * D_SZ + e;
            const f32x4 r0 = *(const f32x4*)rp, r1 = *(const f32x4*)(rp + 4);
            const f32x4 mm0 = *(const f32x4*)(mean + (size_t)c * D_SZ + e);
            const f32x4 mm1 = *(const f32x4*)(mean + (size_t)c * D_SZ + e + 4);
            const f32x4 gg0 = *(const f32x4*)(diag + (size_t)c * D_SZ + e);
            const f32x4 gg1 = *(const f32x4*)(diag + (size_t)c * D_SZ + e + 4);
            short8 p;
            p[0]=(short)f2bf((r0.x-mm0.x)/gg0.x); p[1]=(short)f2bf((r0.y-mm0.y)/gg0.y);
            p[2]=(short)f2bf((r0.z-mm0.z)/gg0.z); p[3]=(short)f2bf((r0.w-mm0.w)/gg0.w);
            p[4]=(short)f2bf((r1.x-mm1.x)/gg1.x); p[5]=(short)f2bf((r1.y-mm1.y)/gg1.y);
            p[6]=(short)f2bf((r1.z-mm1.z)/gg1.z); p[7]=(short)f2bf((r1.w-mm1.w)/gg1.w);
            *(short8*)(dst + s * 8) = p;
        }
    };

    stage_a(aLds, 0);
    stage_x(xLds, 0);
    __syncthreads();
    f32x4 acc[4][4] = {};
    const int fch = l4 ^ ((l15 >> 1) & 3);
    for (int kt = 0; kt < 24; ++kt) {
        const int cur = kt & 1;
        if (kt + 1 < 24) {
            stage_a(aLds + (cur ^ 1) * 128 * 32, kt + 1);
            stage_x(xLds + (cur ^ 1) * 256 * 32, kt + 1);
        }
        const ushort* ab = aLds + cur * 128 * 32;
        const ushort* xb = xLds + cur * 256 * 32;
        short8 xf[4];
        #pragma unroll
        for (int n = 0; n < 4; ++n)
            xf[n] = *(const short8*)(xb + ((wn * 64 + n * 16 + l15) * 4 + fch) * 8);
        #pragma unroll
        for (int m = 0; m < 4; ++m) {
            const short8 af = *(const short8*)(ab + ((wm * 64 + m * 16 + l15) * 4 + fch) * 8);
            #pragma unroll
            for (int n = 0; n < 4; ++n)
                acc[m][n] = __builtin_amdgcn_mfma_f32_16x16x32_bf16(af, xf[n], acc[m][n], 0, 0, 0);
        }
        __syncthreads();
    }
    float v[4] = {};
    #pragma unroll
    for (int m = 0; m < 4; ++m) {
        const int dd = d0 + wm * 64 + m * 16 + l4 * 4;
        const f32x4 mm4 = *(const f32x4*)(mean + (size_t)c * D_SZ + dd);
        const f32x4 gg4 = *(const f32x4*)(diag + (size_t)c * D_SZ + dd);
        f32x4 rd4, md4;
        rd4.x = 1.0f/gg4.x; rd4.y = 1.0f/gg4.y; rd4.z = 1.0f/gg4.z; rd4.w = 1.0f/gg4.w;
        md4.x = mm4.x*rd4.x; md4.y = mm4.y*rd4.y; md4.z = mm4.z*rd4.z; md4.w = mm4.w*rd4.w;
        #pragma unroll
        for (int n = 0; n < 4; ++n) {
            const int bl = b0 + wn * 64 + n * 16 + l15;
            const f32x4 rv = *(const f32x4*)(raw + (size_t)bl * D_SZ + dd);
            v[n] += (0.f - acc[m][n][0]) * (rv.x * rd4.x - md4.x)
                  + (0.f - acc[m][n][1]) * (rv.y * rd4.y - md4.y)
                  + (0.f - acc[m][n][2]) * (rv.z * rd4.z - md4.z)
                  + (0.f - acc[m][n][3]) * (rv.w * rd4.w - md4.w);
        }
    }
    #pragma unroll
    for (int n = 0; n < 4; ++n) {
        v[n] += __shfl_xor(v[n], 16);
        v[n] += __shfl_xor(v[n], 32);
    }
    if (lane < 16) {
        #pragma unroll
        for (int n = 0; n < 4; ++n) red[wid * 64 + n * 16 + l15] = v[n];
    }
    __syncthreads();
    if (tid < 256) {
        const int wno = tid >> 6;
        const int off = tid & 63;
        const float p = red[wno * 64 + off] + red[(4 + wno) * 64 + off];
        atomicAdd(out + (size_t)(b0 + tid) * C_SZ + c, p);
    }
}

extern "C" void kernel_launch(void* const* d_in, const int* in_sizes, int n_in,
                              void* d_out, int out_size, void* d_ws, size_t ws_size,
                              hipStream_t stream) {
    const float* raw  = (const float*)d_in[0];
    const float* mean = (const float*)d_in[1];
    const float* inv  = (const float*)d_in[2];
    const float* diag = (const float*)d_in[3];
    float* out = (float*)d_out;

    const size_t TBL_B = TBL_ELEMS * 4;                    // 307,200
    const size_t AP_B  = AP_ELEMS * 2;                     // 117,964,800
    const size_t RB_B  = RB_ELEMS * 2;                     //   1,572,864
    const size_t need  = 3 * TBL_B + AP_B + RB_B;          // ~120.5 MB

    hipMemsetAsync(d_out, 0, (size_t)out_size * sizeof(float), stream);

    if (ws_size >= need) {
        float*  rdT = (float*)d_ws;
        float*  mdT = (float*)((char*)d_ws + TBL_B);
        float*  wT  = (float*)((char*)d_ws + 2 * TBL_B);
        ushort* ap  = (ushort*)((char*)d_ws + 3 * TBL_B);
        ushort* rb  = (ushort*)((char*)d_ws + 3 * TBL_B + AP_B);
        prep_small<<<75 + 384, 256, 0, stream>>>(mean, diag, raw, rdT, mdT, rb);
        conv_aprime<<<9600, 512, 0, stream>>>(inv, rdT, mdT, ap, wT);
        dim3 grid(8 * 13 * TPC);                           // 1248
        fecam_scores8<<<grid, NTHREADS, 0, stream>>>(raw, rdT, mdT, wT, ap, rb, out);
    } else {
        dim3 grid(8 * 13 * 24);
        fecam_fallback<<<grid, 512, 0, stream>>>(raw, mean, diag, inv, out);
    }
}

// Round 19
// 238.458 us; speedup vs baseline: 1.0011x; 1.0011x over previous
//
#include <hip/hip_runtime.h>
#include <hip/hip_bf16.h>

#define B_SZ 1024
#define C_SZ 100
#define D_SZ 768

#define BM 128                 // d-rows per block (M)
#define BN 256                 // b-cols per block (N)
#define BK 32                  // e per K-step
#define NKT (D_SZ / BK)        // 24
#define NTHREADS 512           // 8 waves: 2(M) x 4(N), wave tile 64x64
#define TPC 24                 // tiles/class: 6 M x 4 N

#define A_HALF (BM * BK)       // 4096 ushorts = 8 KB / buffer
#define X_HALF (BN * BK)       // 8192 ushorts = 16 KB / buffer

#define TBL_ELEMS ((size_t)C_SZ * D_SZ)          // 76,800
#define AP_ELEMS  ((size_t)C_SZ * D_SZ * D_SZ)   // 58,982,400
#define RB_ELEMS  ((size_t)B_SZ * D_SZ)          // 786,432

typedef float f32x4 __attribute__((ext_vector_type(4)));
typedef short short8 __attribute__((ext_vector_type(8)));

__device__ __forceinline__ ushort f2bf(float f) {
    union { __hip_bfloat16 b; ushort u; } cv; cv.b = __float2bfloat16(f); return cv.u;
}
__device__ __forceinline__ float bf2f(ushort u) {
    union { __hip_bfloat16 b; ushort us; } cv; cv.us = u; return __bfloat162float(cv.b);
}
__device__ __forceinline__ void gload_lds16(const void* g, void* l) {
    __builtin_amdgcn_global_load_lds((const __attribute__((address_space(1))) void*)g,
                                     (__attribute__((address_space(3))) void*)l, 16, 0, 0);
}

// ---- prepass A (merged): blocks 0..74 build rd/md tables; 75..458 cast raw->bf16 ----
__global__ __launch_bounds__(256) void prep_small(const float* __restrict__ mean,
                                                  const float* __restrict__ diag,
                                                  const float* __restrict__ raw,
                                                  float* __restrict__ rd,
                                                  float* __restrict__ md,
                                                  ushort* __restrict__ rb) {
    const int bx = (int)blockIdx.x;
    if (bx < 75) {
        const int i = (bx * 256 + (int)threadIdx.x) * 4;
        if (i < (int)TBL_ELEMS) {
            const f32x4 dv = *(const f32x4*)(diag + i);
            const f32x4 mv = *(const f32x4*)(mean + i);
            f32x4 r, m;
            r.x = 1.0f / dv.x; r.y = 1.0f / dv.y; r.z = 1.0f / dv.z; r.w = 1.0f / dv.w;
            m.x = mv.x * r.x;  m.y = mv.y * r.y;  m.z = mv.z * r.z;  m.w = mv.w * r.w;
            *(f32x4*)(rd + i) = r;
            *(f32x4*)(md + i) = m;
        }
    } else {
        const size_t i = (size_t)(bx - 75) * 256 + threadIdx.x;   // 98304 chunks of 8
        const f32x4 v0 = *(const f32x4*)(raw + i * 8);
        const f32x4 v1 = *(const f32x4*)(raw + i * 8 + 4);
        short8 p;
        p[0]=(short)f2bf(v0.x); p[1]=(short)f2bf(v0.y); p[2]=(short)f2bf(v0.z); p[3]=(short)f2bf(v0.w);
        p[4]=(short)f2bf(v1.x); p[5]=(short)f2bf(v1.y); p[6]=(short)f2bf(v1.z); p[7]=(short)f2bf(v1.w);
        *(short8*)(rb + i * 8) = p;
    }
}

// ---- prepass B: A'[c][d][e] = bf16(A*rd_c[e]); w[c][d] = dot(A_row, md_c) ----
__global__ __launch_bounds__(512) void conv_aprime(const float* __restrict__ inv,
                                                   const float* __restrict__ rd,
                                                   const float* __restrict__ md,
                                                   ushort* __restrict__ ap,
                                                   float* __restrict__ w) {
    const int lane = (int)threadIdx.x & 63;
    const int wv   = (int)threadIdx.x >> 6;
    const int ridx = (int)blockIdx.x * 8 + wv;            // c*768+d
    const int c    = ridx / D_SZ;
    const float* arow = inv + (size_t)ridx * D_SZ;
    const float* rdc  = rd + (size_t)c * D_SZ;
    const float* mdc  = md + (size_t)c * D_SZ;
    ushort* aprow = ap + (size_t)ridx * D_SZ;
    float dot = 0.f;
    #pragma unroll
    for (int j = 0; j < 3; ++j) {
        const int e = j * 256 + lane * 4;
        const f32x4 a  = *(const f32x4*)(arow + e);
        const f32x4 r4 = *(const f32x4*)(rdc + e);
        const f32x4 m4 = *(const f32x4*)(mdc + e);
        dot += a.x * m4.x + a.y * m4.y + a.z * m4.z + a.w * m4.w;
        ushort4 p;
        p.x = f2bf(a.x * r4.x); p.y = f2bf(a.y * r4.y);
        p.z = f2bf(a.z * r4.z); p.w = f2bf(a.w * r4.w);
        *(ushort4*)(aprow + e) = p;
    }
    #pragma unroll
    for (int k = 1; k < 64; k <<= 1) dot += __shfl_xor(dot, k);
    if (lane == 0) w[ridx] = dot;
}

// MODE 2: A'/rawbf via gload_lds; fold: out += sum_d x[b,d]*(w[d]-t[d,b])
// == R13/R17 measured best: main ~190us, MfmaUtil 27%, occ 38.8%, FETCH 150MB,
// 0 bank conflicts, absmax 1.0, total 236.3us. All structural neighbors
// measured worse (R8-R16, R18 8-phase). __launch_bounds__(512,4) LOAD-BEARING:
// occ 21->38.5 = 280->192us (R12 vs R13).
// MODE 0: no-ws fallback (f32 sources, divides; w=0 pure -dist form)
template <int MODE>
__global__ __launch_bounds__(NTHREADS, 4) void fecam_scores(
        const float* __restrict__ raw, const float* __restrict__ mean,
        const float* __restrict__ diag, const float* __restrict__ inv,
        const float* __restrict__ rdT, const float* __restrict__ mdT,
        const float* __restrict__ wT,
        const ushort* __restrict__ apAll, const ushort* __restrict__ rbAll,
        float* __restrict__ out) {
    __shared__ __align__(16) ushort aLds[2 * A_HALF];   // 16 KB
    __shared__ __align__(16) ushort xLds[2 * X_HALF];   // 32 KB
    __shared__ float red[8 * 64];                       //  2 KB  -> 50 KB total

    const int tid = (int)threadIdx.x;
    const int bx  = (int)blockIdx.x;

    // XCD-pinned class grouping (validated R3); 4 N-sharers per A' panel
    const int x = bx & 7;
    const int slot0 = bx >> 3;
    const int nCls  = (x < 4) ? 13 : 12;
    const int baseC = (x < 4) ? x * 13 : 52 + (x - 4) * 12;
    const int ci = slot0 / TPC;
    if (ci >= nCls) return;
    const int t  = slot0 % TPC;
    const int c  = baseC + ci;
    const int d0 = (t >> 2) * BM;
    const int b0 = (t & 3) * BN;

    const int lane = tid & 63;
    const int wid  = tid >> 6;
    const int wm   = wid >> 2;      // 0..1 (M)
    const int wn   = wid & 3;       // 0..3 (N)
    const int l15  = lane & 15;
    const int l4   = lane >> 4;

    const ushort* apc = apAll + (size_t)c * D_SZ * D_SZ;
    const float*  Af  = inv + (size_t)c * D_SZ * D_SZ;

    // staging: source-side XOR swizzle q = (s&3) ^ ((r>>1)&3); LDS dest linear.
    // (R7/R13-validated: 0 bank conflicts)
    auto stage_a = [&](ushort* dst, int kt) {
        const int s = tid;                    // 512 slots: 128 rows x 4 chunks
        const int r = s >> 2;
        const int q = (s & 3) ^ ((r >> 1) & 3);
        if constexpr (MODE == 2) {
            gload_lds16(apc + (size_t)(d0 + r) * D_SZ + kt * BK + q * 8, dst + s * 8);
        } else {
            const float* gp = Af + (size_t)(d0 + r) * D_SZ + kt * BK + q * 8;
            const f32x4 a0 = *(const f32x4*)gp;
            const f32x4 a1 = *(const f32x4*)(gp + 4);
            short8 p;
            p[0]=(short)f2bf(a0.x); p[1]=(short)f2bf(a0.y); p[2]=(short)f2bf(a0.z); p[3]=(short)f2bf(a0.w);
            p[4]=(short)f2bf(a1.x); p[5]=(short)f2bf(a1.y); p[6]=(short)f2bf(a1.z); p[7]=(short)f2bf(a1.w);
            *(short8*)(dst + s * 8) = p;
        }
    };
    auto stage_x = [&](ushort* dst, int kt) {
        #pragma unroll
        for (int i = 0; i < 2; ++i) {
            const int s = tid + i * NTHREADS;  // 1024 slots: 256 rows x 4 chunks
            const int r = s >> 2;
            const int q = (s & 3) ^ ((r >> 1) & 3);
            const int e = kt * BK + q * 8;
            if constexpr (MODE == 2) {
                gload_lds16(rbAll + (size_t)(b0 + r) * D_SZ + e, dst + s * 8);
            } else {
                const float* rp = raw + (size_t)(b0 + r) * D_SZ + e;
                const f32x4 r0 = *(const f32x4*)rp, r1 = *(const f32x4*)(rp + 4);
                const f32x4 mm0 = *(const f32x4*)(mean + (size_t)c * D_SZ + e);
                const f32x4 mm1 = *(const f32x4*)(mean + (size_t)c * D_SZ + e + 4);
                const f32x4 gg0 = *(const f32x4*)(diag + (size_t)c * D_SZ + e);
                const f32x4 gg1 = *(const f32x4*)(diag + (size_t)c * D_SZ + e + 4);
                short8 p;
                p[0]=(short)f2bf((r0.x-mm0.x)/gg0.x); p[1]=(short)f2bf((r0.y-mm0.y)/gg0.y);
                p[2]=(short)f2bf((r0.z-mm0.z)/gg0.z); p[3]=(short)f2bf((r0.w-mm0.w)/gg0.w);
                p[4]=(short)f2bf((r1.x-mm1.x)/gg1.x); p[5]=(short)f2bf((r1.y-mm1.y)/gg1.y);
                p[6]=(short)f2bf((r1.z-mm1.z)/gg1.z); p[7]=(short)f2bf((r1.w-mm1.w)/gg1.w);
                *(short8*)(dst + s * 8) = p;
            }
        }
    };

    stage_a(aLds, 0);
    stage_x(xLds, 0);
    __syncthreads();

    f32x4 acc[4][4] = {};   // wave 64(M) x 64(N)

    // frag chunk lane-constant: fch = l4 ^ ((l15>>1)&3)  (matches source swz)
    const int fch = l4 ^ ((l15 >> 1) & 3);
    for (int kt = 0; kt < NKT; ++kt) {
        const int cur = kt & 1;
        if (kt + 1 < NKT) {
            stage_a(aLds + (cur ^ 1) * A_HALF, kt + 1);
            stage_x(xLds + (cur ^ 1) * X_HALF, kt + 1);
        }
        const ushort* ab = aLds + cur * A_HALF;
        const ushort* xb = xLds + cur * X_HALF;
        short8 xf[4];
        #pragma unroll
        for (int n = 0; n < 4; ++n)
            xf[n] = *(const short8*)(xb + ((wn * 64 + n * 16 + l15) * 4 + fch) * 8);
        #pragma unroll
        for (int m = 0; m < 4; ++m) {
            const short8 af = *(const short8*)(ab + ((wm * 64 + m * 16 + l15) * 4 + fch) * 8);
            #pragma unroll
            for (int n = 0; n < 4; ++n)
                acc[m][n] = __builtin_amdgcn_mfma_f32_16x16x32_bf16(af, xf[n], acc[m][n], 0, 0, 0);
        }
        __syncthreads();
    }

    // ---- fold (R9-validated): v[n] = sum_d x[b,d]*(w[d]-t[d,b]), x in f32 ----
    // C/D layout (validated): col(b)=l15, row(d)=l4*4+j
    float v[4] = {};
    #pragma unroll
    for (int m = 0; m < 4; ++m) {
        const int dd = d0 + wm * 64 + m * 16 + l4 * 4;
        f32x4 rd4, md4, w4;
        if constexpr (MODE == 2) {
            rd4 = *(const f32x4*)(rdT + (size_t)c * D_SZ + dd);
            md4 = *(const f32x4*)(mdT + (size_t)c * D_SZ + dd);
            w4  = *(const f32x4*)(wT + (size_t)c * D_SZ + dd);
        } else {
            const f32x4 mm4 = *(const f32x4*)(mean + (size_t)c * D_SZ + dd);
            const f32x4 gg4 = *(const f32x4*)(diag + (size_t)c * D_SZ + dd);
            rd4.x = 1.0f/gg4.x; rd4.y = 1.0f/gg4.y; rd4.z = 1.0f/gg4.z; rd4.w = 1.0f/gg4.w;
            md4.x = mm4.x*rd4.x; md4.y = mm4.y*rd4.y; md4.z = mm4.z*rd4.z; md4.w = mm4.w*rd4.w;
            w4.x = 0.f; w4.y = 0.f; w4.z = 0.f; w4.w = 0.f;
        }
        #pragma unroll
        for (int n = 0; n < 4; ++n) {
            const int bl = b0 + wn * 64 + n * 16 + l15;
            const f32x4 rv = *(const f32x4*)(raw + (size_t)bl * D_SZ + dd);
            v[n] += (w4.x - acc[m][n][0]) * (rv.x * rd4.x - md4.x)
                  + (w4.y - acc[m][n][1]) * (rv.y * rd4.y - md4.y)
                  + (w4.z - acc[m][n][2]) * (rv.z * rd4.z - md4.z)
                  + (w4.w - acc[m][n][3]) * (rv.w * rd4.w - md4.w);
        }
    }
    #pragma unroll
    for (int n = 0; n < 4; ++n) {
        v[n] += __shfl_xor(v[n], 16);
        v[n] += __shfl_xor(v[n], 32);
    }
    if (lane < 16) {
        #pragma unroll
        for (int n = 0; n < 4; ++n) red[wid * 64 + n * 16 + l15] = v[n];
    }
    __syncthreads();
    if (tid < BN) {   // b-local = tid: wn = tid>>6, off = tid&63
        const int wno = tid >> 6;
        const int off = tid & 63;
        const float p = red[wno * 64 + off] + red[(4 + wno) * 64 + off];
        atomicAdd(out + (size_t)(b0 + tid) * C_SZ + c, p);
    }
}

extern "C" void kernel_launch(void* const* d_in, const int* in_sizes, int n_in,
                              void* d_out, int out_size, void* d_ws, size_t ws_size,
                              hipStream_t stream) {
    const float* raw  = (const float*)d_in[0];
    const float* mean = (const float*)d_in[1];
    const float* inv  = (const float*)d_in[2];
    const float* diag = (const float*)d_in[3];
    float* out = (float*)d_out;

    const size_t TBL_B = TBL_ELEMS * 4;                    // 307,200
    const size_t AP_B  = AP_ELEMS * 2;                     // 117,964,800
    const size_t RB_B  = RB_ELEMS * 2;                     //   1,572,864
    const size_t need  = 3 * TBL_B + AP_B + RB_B;          // ~120.5 MB

    hipMemsetAsync(d_out, 0, (size_t)out_size * sizeof(float), stream);
    dim3 grid(8 * 13 * TPC);                               // 2496

    if (ws_size >= need) {
        float*  rdT = (float*)d_ws;
        float*  mdT = (float*)((char*)d_ws + TBL_B);
        float*  wT  = (float*)((char*)d_ws + 2 * TBL_B);
        ushort* ap  = (ushort*)((char*)d_ws + 3 * TBL_B);
        ushort* rb  = (ushort*)((char*)d_ws + 3 * TBL_B + AP_B);
        prep_small<<<75 + 384, 256, 0, stream>>>(mean, diag, raw, rdT, mdT, rb);
        conv_aprime<<<9600, 512, 0, stream>>>(inv, rdT, mdT, ap, wT);
        fecam_scores<2><<<grid, NTHREADS, 0, stream>>>(raw, mean, diag, inv,
                                                       rdT, mdT, wT, ap, rb, out);
    } else {
        fecam_scores<0><<<grid, NTHREADS, 0, stream>>>(raw, mean, diag, inv,
                                                       nullptr, nullptr, nullptr,
                                                       nullptr, nullptr, out);
    }
}